// Round 1
// baseline (709.850 us; speedup 1.0000x reference)
//
#include <hip/hip_runtime.h>
#include <hip/hip_bf16.h>

#define Tt 128
#define Nn 2048
#define Hh 128
#define Dd 128
#define NB 8          // batch rows per block
#define LDA 136       // bf16 LDS row stride (shorts): 128 + 8 pad -> conflict-free frags
#define LDG 388       // fp32 LDS row stride (dwords): 384 + 4 pad, 16B aligned rows

typedef __attribute__((ext_vector_type(8))) short v8s;
typedef __attribute__((ext_vector_type(4))) float v4f;

__device__ __forceinline__ unsigned short f2bf(float f) {
    unsigned int u = __builtin_bit_cast(unsigned int, f);
    u += 0x7FFFu + ((u >> 16) & 1u);   // round-to-nearest-even
    return (unsigned short)(u >> 16);
}

__device__ __forceinline__ v4f mfma16(v8s a, v8s b, v4f c) {
    return __builtin_amdgcn_mfma_f32_16x16x32_bf16(a, b, c, 0, 0, 0);
}

// Load 8 contiguous fp32 of weight row `row` starting at k0, as a bf16 B-fragment.
__device__ __forceinline__ v8s load_wfrag(const float* __restrict__ W, int row, int k0) {
    const v4f* p = (const v4f*)(W + row * 128 + k0);
    v4f a = p[0], b = p[1];
    v8s r;
    r[0] = (short)f2bf(a[0]); r[1] = (short)f2bf(a[1]);
    r[2] = (short)f2bf(a[2]); r[3] = (short)f2bf(a[3]);
    r[4] = (short)f2bf(b[0]); r[5] = (short)f2bf(b[1]);
    r[6] = (short)f2bf(b[2]); r[7] = (short)f2bf(b[3]);
    return r;
}

__device__ __forceinline__ void store_bf4(unsigned short* p, v4f v) {
    unsigned int lo = ((unsigned int)f2bf(v[1]) << 16) | (unsigned int)f2bf(v[0]);
    unsigned int hi = ((unsigned int)f2bf(v[3]) << 16) | (unsigned int)f2bf(v[2]);
    uint2 d; d.x = lo; d.y = hi;
    *(uint2*)p = d;   // 8B aligned by construction (jj*2 multiple of 8, LDA*2=272)
}

__device__ __forceinline__ float sigm(float x) {
    return __frcp_rn(1.f + __expf(-x));
}
__device__ __forceinline__ float tanh_f(float x) {
    return 2.f * __frcp_rn(1.f + __expf(-2.f * x)) - 1.f;
}

__global__ __launch_bounds__(256, 1)
void rppo_fused(const float* __restrict__ x, const float* __restrict__ hxs,
                const float* __restrict__ masks,
                const float* __restrict__ ln1_w, const float* __restrict__ ln1_b,
                const float* __restrict__ W1, const float* __restrict__ b1,
                const float* __restrict__ W2, const float* __restrict__ b2,
                const float* __restrict__ Wih, const float* __restrict__ bih,
                const float* __restrict__ Whh, const float* __restrict__ bhh,
                const float* __restrict__ ln2_w, const float* __restrict__ ln2_b,
                float* __restrict__ out)
{
    __shared__ unsigned short fbuf[16 * LDA];   // LN1 output (A of GEMM1)
    __shared__ unsigned short abuf[16 * LDA];   // GEMM1 out  (A of GEMM2)
    __shared__ unsigned short bbuf[16 * LDA];   // GEMM2 out  (A of GEMM3)
    __shared__ unsigned short hbuf[16 * LDA];   // masked h   (A of scan GEMM)
    __shared__ float gibuf[8 * LDG];            // GEMM3 out (+b_ih)
    __shared__ float ghbuf[8 * LDG];            // scan GEMM out (+b_hh)
    __shared__ float mbuf[Tt * NB];             // masks for this block's batch rows

    const int tid  = threadIdx.x;
    const int wave = tid >> 6;
    const int lane = tid & 63;
    const int l16  = lane & 15;
    const int quad = lane >> 4;
    const int bb   = tid >> 5;          // batch row 0..7 (elementwise mapping)
    const int jj   = (tid & 31) << 2;   // col 0,4,...,124
    const int n0   = blockIdx.x * NB;

    // ---- weight fragments in registers (bf16), B[k][n] = W[n][k] ----
    v8s w1f[2][4], w2f[2][4], wif[6][4], whf[6][4];
#pragma unroll
    for (int c = 0; c < 2; ++c)
#pragma unroll
        for (int kk = 0; kk < 4; ++kk) {
            int k0 = kk * 32 + quad * 8;
            int rowc = (2 * wave + c) * 16 + l16;
            w1f[c][kk] = load_wfrag(W1, rowc, k0);
            w2f[c][kk] = load_wfrag(W2, rowc, k0);
        }
#pragma unroll
    for (int c = 0; c < 6; ++c)
#pragma unroll
        for (int kk = 0; kk < 4; ++kk) {
            int k0 = kk * 32 + quad * 8;
            int rowc = (6 * wave + c) * 16 + l16;
            wif[c][kk] = load_wfrag(Wih, rowc, k0);
            whf[c][kk] = load_wfrag(Whh, rowc, k0);
        }

    float b1r[2], b2r[2];
#pragma unroll
    for (int c = 0; c < 2; ++c) {
        b1r[c] = b1[(2 * wave + c) * 16 + l16];
        b2r[c] = b2[(2 * wave + c) * 16 + l16];
    }
    float bir[6], bhr[6];
#pragma unroll
    for (int c = 0; c < 6; ++c) {
        bir[c] = bih[(6 * wave + c) * 16 + l16];
        bhr[c] = bhh[(6 * wave + c) * 16 + l16];
    }

    const v4f ln1w = *(const v4f*)(ln1_w + jj);
    const v4f ln1b = *(const v4f*)(ln1_b + jj);
    const v4f ln2w = *(const v4f*)(ln2_w + jj);
    const v4f ln2b = *(const v4f*)(ln2_b + jj);

    for (int i = tid; i < Tt * NB; i += 256) {
        int t = i >> 3, b = i & 7;
        mbuf[i] = masks[t * Nn + n0 + b];
    }

    // h0 masked by m_0, kept in registers (fp32) + bf16 copy in LDS
    v4f h = *(const v4f*)(hxs + (size_t)(n0 + bb) * Hh + jj);
    h *= masks[n0 + bb];
    store_bf4(hbuf + bb * LDA + jj, h);

    // prefetch x for t=0
    v4f xv = *(const v4f*)(x + (size_t)(n0 + bb) * Dd + jj);

    __syncthreads();

    for (int t = 0; t < Tt; ++t) {
        // ---------- phase 1: LN1 -> fbuf (bf16) ----------
        {
            float s  = xv[0] + xv[1] + xv[2] + xv[3];
            float ss = xv[0]*xv[0] + xv[1]*xv[1] + xv[2]*xv[2] + xv[3]*xv[3];
#pragma unroll
            for (int m = 1; m < 32; m <<= 1) {
                s  += __shfl_xor(s,  m, 64);
                ss += __shfl_xor(ss, m, 64);
            }
            float mu = s * (1.f / 128.f);
            float rs = __frsqrt_rn(ss * (1.f / 128.f) - mu * mu + 1e-5f);
            v4f f;
#pragma unroll
            for (int i = 0; i < 4; ++i) f[i] = (xv[i] - mu) * rs * ln1w[i] + ln1b[i];
            store_bf4(fbuf + bb * LDA + jj, f);
        }
        if (t + 1 < Tt)   // prefetch next step's x rows
            xv = *(const v4f*)(x + ((size_t)(t + 1) * Nn + n0 + bb) * Dd + jj);
        __syncthreads();

        // ---------- phase 2: GEMM1: fbuf @ W1^T + b1 -> abuf ----------
        {
            v8s af[4];
#pragma unroll
            for (int kk = 0; kk < 4; ++kk)
                af[kk] = *(const v8s*)(fbuf + l16 * LDA + kk * 32 + quad * 8);
            v4f acc[2] = {{0.f,0.f,0.f,0.f},{0.f,0.f,0.f,0.f}};
#pragma unroll
            for (int c = 0; c < 2; ++c)
#pragma unroll
                for (int kk = 0; kk < 4; ++kk)
                    acc[c] = mfma16(af[kk], w1f[c][kk], acc[c]);
#pragma unroll
            for (int c = 0; c < 2; ++c) {
                int col = (2 * wave + c) * 16 + l16;
#pragma unroll
                for (int r = 0; r < 4; ++r) {
                    int row = quad * 4 + r;
                    if (row < 8) abuf[row * LDA + col] = f2bf(acc[c][r] + b1r[c]);
                }
            }
        }
        __syncthreads();

        // ---------- phase 3: GEMM2: abuf @ W2^T + b2 -> bbuf ----------
        {
            v8s af[4];
#pragma unroll
            for (int kk = 0; kk < 4; ++kk)
                af[kk] = *(const v8s*)(abuf + l16 * LDA + kk * 32 + quad * 8);
            v4f acc[2] = {{0.f,0.f,0.f,0.f},{0.f,0.f,0.f,0.f}};
#pragma unroll
            for (int c = 0; c < 2; ++c)
#pragma unroll
                for (int kk = 0; kk < 4; ++kk)
                    acc[c] = mfma16(af[kk], w2f[c][kk], acc[c]);
#pragma unroll
            for (int c = 0; c < 2; ++c) {
                int col = (2 * wave + c) * 16 + l16;
#pragma unroll
                for (int r = 0; r < 4; ++r) {
                    int row = quad * 4 + r;
                    if (row < 8) bbuf[row * LDA + col] = f2bf(acc[c][r] + b2r[c]);
                }
            }
        }
        __syncthreads();

        // ---------- phase 4: GEMM3 (gi) + scan GEMM (gh), both 384 cols ----------
        {
            v8s af[4], hf[4];
#pragma unroll
            for (int kk = 0; kk < 4; ++kk) {
                af[kk] = *(const v8s*)(bbuf + l16 * LDA + kk * 32 + quad * 8);
                hf[kk] = *(const v8s*)(hbuf + l16 * LDA + kk * 32 + quad * 8);
            }
            v4f ga[6], ha[6];
#pragma unroll
            for (int c = 0; c < 6; ++c) {
                ga[c] = (v4f){0.f,0.f,0.f,0.f};
                ha[c] = (v4f){0.f,0.f,0.f,0.f};
            }
#pragma unroll
            for (int c = 0; c < 6; ++c)
#pragma unroll
                for (int kk = 0; kk < 4; ++kk) {
                    ga[c] = mfma16(af[kk], wif[c][kk], ga[c]);
                    ha[c] = mfma16(hf[kk], whf[c][kk], ha[c]);
                }
#pragma unroll
            for (int c = 0; c < 6; ++c) {
                int col = (6 * wave + c) * 16 + l16;
#pragma unroll
                for (int r = 0; r < 4; ++r) {
                    int row = quad * 4 + r;
                    if (row < 8) {
                        gibuf[row * LDG + col] = ga[c][r] + bir[c];
                        ghbuf[row * LDG + col] = ha[c][r] + bhr[c];
                    }
                }
            }
        }
        __syncthreads();

        // ---------- phase 5: GRU nonlinearity + LN2 + stores ----------
        {
            const float* gb = gibuf + bb * LDG + jj;
            const float* hb = ghbuf + bb * LDG + jj;
            v4f ir  = *(const v4f*)(gb);
            v4f iz  = *(const v4f*)(gb + 128);
            v4f inn = *(const v4f*)(gb + 256);
            v4f hr  = *(const v4f*)(hb);
            v4f hz  = *(const v4f*)(hb + 128);
            v4f hn  = *(const v4f*)(hb + 256);
            v4f hnew;
#pragma unroll
            for (int i = 0; i < 4; ++i) {
                float r = sigm(ir[i] + hr[i]);
                float z = sigm(iz[i] + hz[i]);
                float n = tanh_f(inn[i] + r * hn[i]);
                hnew[i] = n + z * (h[i] - n);   // (1-z)*n + z*h
            }
            float s2  = hnew[0] + hnew[1] + hnew[2] + hnew[3];
            float ss2 = hnew[0]*hnew[0] + hnew[1]*hnew[1] + hnew[2]*hnew[2] + hnew[3]*hnew[3];
#pragma unroll
            for (int m = 1; m < 32; m <<= 1) {
                s2  += __shfl_xor(s2,  m, 64);
                ss2 += __shfl_xor(ss2, m, 64);
            }
            float mu2 = s2 * (1.f / 128.f);
            float rs2 = __frsqrt_rn(ss2 * (1.f / 128.f) - mu2 * mu2 + 1e-5f);
            v4f o;
#pragma unroll
            for (int i = 0; i < 4; ++i) o[i] = (hnew[i] - mu2) * rs2 * ln2w[i] + ln2b[i];
            *(v4f*)(out + ((size_t)t * Nn + n0 + bb) * Hh + jj) = o;

            if (t + 1 < Tt) {
                float mt = mbuf[(t + 1) * NB + bb];
                h = hnew * mt;                       // mask applied entering next step
                store_bf4(hbuf + bb * LDA + jj, h);  // bf16 A-copy for scan GEMM
            } else {
                // hT = final (unmasked) h_new
                *(v4f*)(out + (size_t)Tt * Nn * Hh + (size_t)(n0 + bb) * Hh + jj) = hnew;
            }
        }
        // next iteration's phase-1..3 barriers separate hbuf write from its phase-4 read
    }
}

extern "C" void kernel_launch(void* const* d_in, const int* in_sizes, int n_in,
                              void* d_out, int out_size, void* d_ws, size_t ws_size,
                              hipStream_t stream) {
    const float* x     = (const float*)d_in[0];
    const float* hxs   = (const float*)d_in[1];
    const float* masks = (const float*)d_in[2];
    const float* ln1w  = (const float*)d_in[3];
    const float* ln1b  = (const float*)d_in[4];
    const float* W1    = (const float*)d_in[5];
    const float* b1    = (const float*)d_in[6];
    const float* W2    = (const float*)d_in[7];
    const float* b2    = (const float*)d_in[8];
    const float* Wih   = (const float*)d_in[9];
    const float* bih   = (const float*)d_in[10];
    const float* Whh   = (const float*)d_in[11];
    const float* bhh   = (const float*)d_in[12];
    const float* ln2w  = (const float*)d_in[13];
    const float* ln2b  = (const float*)d_in[14];
    float* out = (float*)d_out;

    hipLaunchKernelGGL(rppo_fused, dim3(Nn / NB), dim3(256), 0, stream,
                       x, hxs, masks, ln1w, ln1b, W1, b1, W2, b2,
                       Wih, bih, Whh, bhh, ln2w, ln2b, out);
}

// Round 5
// 573.445 us; speedup vs baseline: 1.2379x; 1.2379x over previous
//
#include <hip/hip_runtime.h>
#include <hip/hip_bf16.h>

#define Tt 128
#define Nn 2048
#define Hh 128
#define Dd 128
#define NB 8          // batch rows per block
#define LDA 136       // bf16 LDS row stride (shorts): 128 + 8 pad
#define LDG 388       // fp32 LDS row stride (dwords): 384 + 4 pad

typedef __attribute__((ext_vector_type(8))) short v8s;
typedef __attribute__((ext_vector_type(4))) float v4f;

__device__ __forceinline__ unsigned short f2bf(float f) {
    unsigned int u = __builtin_bit_cast(unsigned int, f);
    u += 0x7FFFu + ((u >> 16) & 1u);   // round-to-nearest-even
    return (unsigned short)(u >> 16);
}

__device__ __forceinline__ v4f mfma_bf(v8s a, v8s b, v4f c) {
    return __builtin_amdgcn_mfma_f32_16x16x32_bf16(a, b, c, 0, 0, 0);
}

__device__ __forceinline__ v8s load_wfrag_bf(const float* __restrict__ W, int row, int k0) {
    const v4f* p = (const v4f*)(W + row * 128 + k0);
    v4f a = p[0], b = p[1];
    v8s r;
    r[0] = (short)f2bf(a[0]); r[1] = (short)f2bf(a[1]);
    r[2] = (short)f2bf(a[2]); r[3] = (short)f2bf(a[3]);
    r[4] = (short)f2bf(b[0]); r[5] = (short)f2bf(b[1]);
    r[6] = (short)f2bf(b[2]); r[7] = (short)f2bf(b[3]);
    return r;
}

__device__ __forceinline__ void store_bf4(unsigned short* p, v4f v) {
    unsigned int lo = ((unsigned int)f2bf(v[1]) << 16) | (unsigned int)f2bf(v[0]);
    unsigned int hi = ((unsigned int)f2bf(v[3]) << 16) | (unsigned int)f2bf(v[2]);
    uint2 d; d.x = lo; d.y = hi;
    *(uint2*)p = d;   // 8B aligned (col4*2 bytes is a multiple of 8)
}

__device__ __forceinline__ float sigm(float x) { return __frcp_rn(1.f + __expf(-x)); }
__device__ __forceinline__ float tanh_f(float x) {
    return 2.f * __frcp_rn(1.f + __expf(-2.f * x)) - 1.f;
}

// Pipelined monolith: 512 threads = 8 waves.
//   P = waves 0-3: step t=i   : LN1 -> G1 -> G2 -> gi  (holds W1,W2,Wih frags)
//   Q = waves 4-7: step t=i-1 : GRU nonlin + LN2 + out; then gh(t=i) (holds Whh frags)
// Numerics are bit-identical to the R1 kernel (same rounding points, same
// reduction trees); the two streams overlap under the same 4 barriers/step.
__global__ __launch_bounds__(512, 2)
void rppo_pipe(const float* __restrict__ x, const float* __restrict__ hxs,
               const float* __restrict__ masks,
               const float* __restrict__ ln1_w, const float* __restrict__ ln1_b,
               const float* __restrict__ W1, const float* __restrict__ b1,
               const float* __restrict__ W2, const float* __restrict__ b2,
               const float* __restrict__ Wih, const float* __restrict__ bih,
               const float* __restrict__ Whh, const float* __restrict__ bhh,
               const float* __restrict__ ln2_w, const float* __restrict__ ln2_b,
               float* __restrict__ out)
{
    __shared__ unsigned short fbuf[16 * LDA];   // LN1 out       (A of G1)
    __shared__ unsigned short abuf[16 * LDA];   // G1 out        (A of G2)
    __shared__ unsigned short bbuf[16 * LDA];   // G2 out        (A of gi)
    __shared__ unsigned short hbuf[16 * LDA];   // masked h      (A of gh)
    __shared__ float gibuf[8 * LDG];            // gi(t) + b_ih
    __shared__ float ghbuf[8 * LDG];            // gh(t) + b_hh
    __shared__ float mbuf[Tt * NB];             // this block's masks

    const int tid  = threadIdx.x;
    const int wave = tid >> 6;
    const int lane = tid & 63;
    const int l16  = lane & 15;
    const int quad = lane >> 4;
    const int arow = l16 & 7;
    const int wsub = wave & 3;
    const bool isP = (wave < 4);
    const int n0   = blockIdx.x * NB;

    // ---- weight fragments, shared register array (wave-uniform fill) ----
    // P: wreg[0..1]=W1 tiles, wreg[2..3]=W2 tiles, wreg[4..9]=Wih tiles
    // Q: wreg[4..9]=Whh tiles
    v8s wreg[10][4];
    float brA[2], brB[2], brC[6];
    if (isP) {
#pragma unroll
        for (int c = 0; c < 2; ++c) {
            int rowc = (2 * wsub + c) * 16 + l16;
            brA[c] = b1[rowc];
            brB[c] = b2[rowc];
#pragma unroll
            for (int kk = 0; kk < 4; ++kk) {
                int k0 = kk * 32 + quad * 8;
                wreg[c][kk]     = load_wfrag_bf(W1, rowc, k0);
                wreg[2 + c][kk] = load_wfrag_bf(W2, rowc, k0);
            }
        }
#pragma unroll
        for (int c = 0; c < 6; ++c) {
            int rowc = (6 * wsub + c) * 16 + l16;
            brC[c] = bih[rowc];
#pragma unroll
            for (int kk = 0; kk < 4; ++kk)
                wreg[4 + c][kk] = load_wfrag_bf(Wih, rowc, kk * 32 + quad * 8);
        }
    } else {
#pragma unroll
        for (int c = 0; c < 6; ++c) {
            int rowc = (6 * wsub + c) * 16 + l16;
            brC[c] = bhh[rowc];
#pragma unroll
            for (int kk = 0; kk < 4; ++kk)
                wreg[4 + c][kk] = load_wfrag_bf(Whh, rowc, kk * 32 + quad * 8);
        }
    }

    // masks for this block
    for (int i = tid; i < Tt * NB; i += 512) {
        int t = i >> 3, b = i & 7;
        mbuf[i] = masks[t * Nn + n0 + b];
    }

    // ---- per-stream element mappings ----
    // P LN1: row8 = tid>>5 (0..7), col4 = (tid&31)*4   [tid<256]
    // Q tail: prow = (wave-4)*2 + (lane>>5), col4 = (lane&31)*4
    const int col4 = (tid & 31) << 2;
    const int row8 = tid >> 5;                 // valid for P (tid<256)
    const int prow = (wave - 4) * 2 + (lane >> 5);   // valid for Q

    v4f ln1w, ln1b, ln2w, ln2b, h, xv;
    if (isP) {
        ln1w = *(const v4f*)(ln1_w + col4);
        ln1b = *(const v4f*)(ln1_b + col4);
        // prefetch x for t=0
        xv = *(const v4f*)(x + (size_t)(n0 + row8) * Dd + col4);
    } else {
        ln2w = *(const v4f*)(ln2_w + col4);
        ln2b = *(const v4f*)(ln2_b + col4);
        // h0 masked by m_0 -> regs + bf16 LDS copy
        h = *(const v4f*)(hxs + (size_t)(n0 + prow) * Hh + col4);
        h *= masks[n0 + prow];
        store_bf4(hbuf + prow * LDA + col4, h);
    }
    __syncthreads();

    for (int i = 0; i <= Tt; ++i) {
        // ========== seg A:  P: LN1(t=i) -> fbuf   |   Q: GRU tail(t=i-1) ==========
        if (isP) {
            if (i < Tt) {
                float s  = xv[0] + xv[1] + xv[2] + xv[3];
                float ss = xv[0]*xv[0] + xv[1]*xv[1] + xv[2]*xv[2] + xv[3]*xv[3];
#pragma unroll
                for (int m = 1; m < 32; m <<= 1) {
                    s  += __shfl_xor(s,  m, 64);
                    ss += __shfl_xor(ss, m, 64);
                }
                float mu = s * (1.f / 128.f);
                float rs = __frsqrt_rn(ss * (1.f / 128.f) - mu * mu + 1e-5f);
                v4f f;
#pragma unroll
                for (int e = 0; e < 4; ++e) f[e] = (xv[e] - mu) * rs * ln1w[e] + ln1b[e];
                store_bf4(fbuf + row8 * LDA + col4, f);
                if (i + 1 < Tt)
                    xv = *(const v4f*)(x + ((size_t)(i + 1) * Nn + n0 + row8) * Dd + col4);
            }
        } else if (i >= 1) {
            const int t = i - 1;
            const float* gb = gibuf + prow * LDG + col4;
            const float* hb = ghbuf + prow * LDG + col4;
            v4f ir  = *(const v4f*)(gb);
            v4f iz  = *(const v4f*)(gb + 128);
            v4f inn = *(const v4f*)(gb + 256);
            v4f hr  = *(const v4f*)(hb);
            v4f hz  = *(const v4f*)(hb + 128);
            v4f hn  = *(const v4f*)(hb + 256);
            v4f hnew;
#pragma unroll
            for (int e = 0; e < 4; ++e) {
                float r = sigm(ir[e] + hr[e]);
                float z = sigm(iz[e] + hz[e]);
                float n = tanh_f(inn[e] + r * hn[e]);
                hnew[e] = n + z * (h[e] - n);   // (1-z)*n + z*h
            }
            float s2  = hnew[0] + hnew[1] + hnew[2] + hnew[3];
            float ss2 = hnew[0]*hnew[0] + hnew[1]*hnew[1] + hnew[2]*hnew[2] + hnew[3]*hnew[3];
#pragma unroll
            for (int m = 1; m < 32; m <<= 1) {
                s2  += __shfl_xor(s2,  m, 64);
                ss2 += __shfl_xor(ss2, m, 64);
            }
            float mu2 = s2 * (1.f / 128.f);
            float rs2 = __frsqrt_rn(ss2 * (1.f / 128.f) - mu2 * mu2 + 1e-5f);
            v4f o;
#pragma unroll
            for (int e = 0; e < 4; ++e) o[e] = (hnew[e] - mu2) * rs2 * ln2w[e] + ln2b[e];
            *(v4f*)(out + ((size_t)t * Nn + n0 + prow) * Hh + col4) = o;

            if (t + 1 < Tt) {
                float mt = mbuf[(t + 1) * NB + prow];
                h = hnew * mt;                         // masked h entering step t+1
                store_bf4(hbuf + prow * LDA + col4, h);
            } else {
                *(v4f*)(out + (size_t)Tt * Nn * Hh + (size_t)(n0 + prow) * Hh + col4) = hnew;
            }
        }
        __syncthreads();   // B1

        // ========== seg B:  P: G1 fbuf -> abuf ==========
        if (isP && i < Tt) {
            v8s af[4];
#pragma unroll
            for (int kk = 0; kk < 4; ++kk)
                af[kk] = *(const v8s*)(fbuf + arow * LDA + kk * 32 + quad * 8);
            v4f acc[2] = {{0.f,0.f,0.f,0.f},{0.f,0.f,0.f,0.f}};
#pragma unroll
            for (int c = 0; c < 2; ++c)
#pragma unroll
                for (int kk = 0; kk < 4; ++kk)
                    acc[c] = mfma_bf(af[kk], wreg[c][kk], acc[c]);
#pragma unroll
            for (int c = 0; c < 2; ++c) {
                int col = (2 * wsub + c) * 16 + l16;
#pragma unroll
                for (int rr = 0; rr < 4; ++rr) {
                    int row = quad * 4 + rr;
                    if (row < 8) abuf[row * LDA + col] = f2bf(acc[c][rr] + brA[c]);
                }
            }
        }
        __syncthreads();   // B2

        // ========== seg C:  P: G2 abuf -> bbuf ==========
        if (isP && i < Tt) {
            v8s af[4];
#pragma unroll
            for (int kk = 0; kk < 4; ++kk)
                af[kk] = *(const v8s*)(abuf + arow * LDA + kk * 32 + quad * 8);
            v4f acc[2] = {{0.f,0.f,0.f,0.f},{0.f,0.f,0.f,0.f}};
#pragma unroll
            for (int c = 0; c < 2; ++c)
#pragma unroll
                for (int kk = 0; kk < 4; ++kk)
                    acc[c] = mfma_bf(af[kk], wreg[2 + c][kk], acc[c]);
#pragma unroll
            for (int c = 0; c < 2; ++c) {
                int col = (2 * wsub + c) * 16 + l16;
#pragma unroll
                for (int rr = 0; rr < 4; ++rr) {
                    int row = quad * 4 + rr;
                    if (row < 8) bbuf[row * LDA + col] = f2bf(acc[c][rr] + brB[c]);
                }
            }
        }
        __syncthreads();   // B3

        // ========== seg D:  P: gi(t=i) -> gibuf   |   Q: gh(t=i) -> ghbuf ==========
        if (i < Tt) {
            const unsigned short* srcA = isP ? bbuf : hbuf;
            float* dst = isP ? gibuf : ghbuf;
            v8s af[4];
#pragma unroll
            for (int kk = 0; kk < 4; ++kk)
                af[kk] = *(const v8s*)(srcA + arow * LDA + kk * 32 + quad * 8);
            v4f acc[6];
#pragma unroll
            for (int c = 0; c < 6; ++c) acc[c] = (v4f){0.f,0.f,0.f,0.f};
#pragma unroll
            for (int c = 0; c < 6; ++c)
#pragma unroll
                for (int kk = 0; kk < 4; ++kk)
                    acc[c] = mfma_bf(af[kk], wreg[4 + c][kk], acc[c]);
#pragma unroll
            for (int c = 0; c < 6; ++c) {
                int col = (6 * wsub + c) * 16 + l16;
#pragma unroll
                for (int rr = 0; rr < 4; ++rr) {
                    int row = quad * 4 + rr;
                    if (row < 8) dst[row * LDG + col] = acc[c][rr] + brC[c];
                }
            }
        }
        __syncthreads();   // B4
    }
}

extern "C" void kernel_launch(void* const* d_in, const int* in_sizes, int n_in,
                              void* d_out, int out_size, void* d_ws, size_t ws_size,
                              hipStream_t stream) {
    const float* x     = (const float*)d_in[0];
    const float* hxs   = (const float*)d_in[1];
    const float* masks = (const float*)d_in[2];
    const float* ln1w  = (const float*)d_in[3];
    const float* ln1b  = (const float*)d_in[4];
    const float* W1    = (const float*)d_in[5];
    const float* b1    = (const float*)d_in[6];
    const float* W2    = (const float*)d_in[7];
    const float* b2    = (const float*)d_in[8];
    const float* Wih   = (const float*)d_in[9];
    const float* bih   = (const float*)d_in[10];
    const float* Whh   = (const float*)d_in[11];
    const float* bhh   = (const float*)d_in[12];
    const float* ln2w  = (const float*)d_in[13];
    const float* ln2b  = (const float*)d_in[14];
    float* out = (float*)d_out;

    hipLaunchKernelGGL(rppo_pipe, dim3(Nn / NB), dim3(512), 0, stream,
                       x, hxs, masks, ln1w, ln1b, W1, b1, W2, b2,
                       Wih, bih, Whh, bhh, ln2w, ln2b, out);
}